// Round 7
// baseline (308.178 us; speedup 1.0000x reference)
//
#include <hip/hip_runtime.h>
#include <math.h>

#define N_ATOMS 20000
#define N_EDGES 200000
#define CH 64
#define NB 8
#define NK 11
#define COPY_BLOCKS 12500   // 200000*64/4 float4 / (64 threads * 4 each)

// ---------------------------------------------------------------
// Kernel 1: histogram of idx_i
__global__ __launch_bounds__(256) void hist_kernel(
    const int* __restrict__ idx_i, int* __restrict__ counts)
{
    int e = blockIdx.x * blockDim.x + threadIdx.x;
    if (e >= N_EDGES) return;
    atomicAdd(&counts[idx_i[e]], 1);
}

// ---------------------------------------------------------------
// Kernel 2: exclusive scan (single 1024-thread block)
__global__ __launch_bounds__(1024) void scan_kernel(
    const int* __restrict__ counts, int* __restrict__ offsets,
    int* __restrict__ cursor)
{
    __shared__ int part[1024];
    const int CHUNK = 20;  // 1024*20 = 20480 >= 20000
    int t = threadIdx.x;
    int beg = t * CHUNK;
    int s = 0;
    for (int k = 0; k < CHUNK; ++k) {
        int idx = beg + k;
        if (idx < N_ATOMS) s += counts[idx];
    }
    part[t] = s;
    __syncthreads();
    for (int off = 1; off < 1024; off <<= 1) {
        int v = (t >= off) ? part[t - off] : 0;
        __syncthreads();
        part[t] += v;
        __syncthreads();
    }
    int run = part[t] - s;
    for (int k = 0; k < CHUNK; ++k) {
        int idx = beg + k;
        if (idx < N_ATOMS) {
            offsets[idx] = run;
            cursor[idx] = run;
            run += counts[idx];
        }
    }
    if (t == 0) offsets[N_ATOMS] = N_EDGES;
}

// ---------------------------------------------------------------
// Kernel 3: scatter into CSR order, computing geometry on the fly
// ge4[p][0..2] = {rh, rbf0..7, pad}; jlist[p] = idx_j[e]
__global__ __launch_bounds__(256) void scatter_geom_kernel(
    const float* __restrict__ rij, const int* __restrict__ idx_i,
    const int* __restrict__ idx_j, int* __restrict__ cursor,
    int* __restrict__ jlist, float4* __restrict__ ge4)
{
    int e = blockIdx.x * blockDim.x + threadIdx.x;
    if (e >= N_EDGES) return;

    float rx = rij[e * 3 + 0];
    float ry = rij[e * 3 + 1];
    float rz = rij[e * 3 + 2];
    float d = sqrtf(rx * rx + ry * ry + rz * rz);
    float inv = 1.0f / (d + 1e-12f);

    float dc = fminf(d, 5.0f);
    float fcut = 0.5f * (cosf(3.14159265358979323846f * dc * 0.2f) + 1.0f);

    float rbf[NB];
#pragma unroll
    for (int b = 0; b < NB; ++b) {
        float mu = (5.0f / 7.0f) * (float)b;
        float t = d - mu;
        rbf[b] = expf(-2.0f * t * t) * fcut;
    }

    int p = atomicAdd(&cursor[idx_i[e]], 1);
    jlist[p] = idx_j[e];
    ge4[p * 3 + 0] = make_float4(rx * inv, ry * inv, rz * inv, rbf[0]);
    ge4[p * 3 + 1] = make_float4(rbf[1], rbf[2], rbf[3], rbf[4]);
    ge4[p * 3 + 2] = make_float4(rbf[5], rbf[6], rbf[7], 0.f);
}

// ---------------------------------------------------------------
// Kernel 4: fused gather + SI matmul + nonlinearity + residual.
// One 64-thread block (1 wave) per atom, lane = channel.
// __launch_bounds__(64, 1): min-waves-per-EU = 1 -> full 512-VGPR
// budget, occupancy target 1. This is the A/B vs round 5's (64,2)
// (identical code, VGPR stuck at 76 + scratch spill, 276 us).
// The asm pin forbids rematerializing the 88 weight loads.
__global__ __launch_bounds__(64, 1) void atom_fused_kernel(
    const float* __restrict__ node0, const float* __restrict__ node1,
    const float* __restrict__ node2,
    const int* __restrict__ jlist, const int* __restrict__ offsets,
    const float4* __restrict__ ge4, const float* __restrict__ rbf_w,
    const float* __restrict__ si_w0, const float* __restrict__ si_b0,
    const float* __restrict__ si_w1, const float* __restrict__ si_w2,
    const float* __restrict__ nl_w1, const float* __restrict__ nl_b1,
    const float* __restrict__ nl_w2, const float* __restrict__ nl_b2,
    float* __restrict__ out0, float* __restrict__ out1, float* __restrict__ out2,
    const float4* __restrict__ edge0_in, float4* __restrict__ edge0_out)
{
    int n = blockIdx.x;
    int c = threadIdx.x;  // 0..63

    if (n >= N_ATOMS) {
        int cb = n - N_ATOMS;
        size_t base = (size_t)cb * 256;
#pragma unroll
        for (int k = 0; k < 4; ++k)
            edge0_out[base + k * 64 + c] = edge0_in[base + k * 64 + c];
        return;
    }

    __shared__ float abuf[CH][13];

    // rbf mixing weights: wreg[k*NB+b] = rbf_w[k][b][c], pinned resident.
    float wreg[NK * NB];
#pragma unroll
    for (int kb = 0; kb < NK * NB; ++kb) {
        wreg[kb] = rbf_w[kb * CH + c];
        asm volatile("" : "+v"(wreg[kb]));
    }

    float a0 = 0.f;
    float a1[3] = {0.f, 0.f, 0.f};
    float a2[9] = {0.f, 0.f, 0.f, 0.f, 0.f, 0.f, 0.f, 0.f, 0.f};

    int beg = offsets[n];
    int end = offsets[n + 1];

    // software pipeline: geom + h for edge p, j for edge p+1
    float4 g0, g1v, g2v;
    float h0 = 0.f, h1[3] = {0.f, 0.f, 0.f};
    float h2[9] = {0.f, 0.f, 0.f, 0.f, 0.f, 0.f, 0.f, 0.f, 0.f};
    int jnx = 0;

    if (beg < end) {
        int j = jlist[beg];
        g0 = ge4[beg * 3 + 0];
        g1v = ge4[beg * 3 + 1];
        g2v = ge4[beg * 3 + 2];
        h0 = node0[(size_t)j * CH + c];
#pragma unroll
        for (int x = 0; x < 3; ++x) h1[x] = node1[((size_t)j * CH + c) * 3 + x];
#pragma unroll
        for (int q = 0; q < 9; ++q) h2[q] = node2[((size_t)j * CH + c) * 9 + q];
        jnx = (beg + 1 < end) ? jlist[beg + 1] : 0;
    }

    for (int p = beg; p < end; ++p) {
        float rh[3] = {g0.x, g0.y, g0.z};
        float rbf[NB] = {g0.w, g1v.x, g1v.y, g1v.z, g1v.w, g2v.x, g2v.y, g2v.z};
        float ch0 = h0;
        float ch1[3] = {h1[0], h1[1], h1[2]};
        float ch2[9];
#pragma unroll
        for (int q = 0; q < 9; ++q) ch2[q] = h2[q];

        if (p + 1 < end) {
            int j2 = jnx;
            g0 = ge4[(p + 1) * 3 + 0];
            g1v = ge4[(p + 1) * 3 + 1];
            g2v = ge4[(p + 1) * 3 + 2];
            h0 = node0[(size_t)j2 * CH + c];
#pragma unroll
            for (int x = 0; x < 3; ++x) h1[x] = node1[((size_t)j2 * CH + c) * 3 + x];
#pragma unroll
            for (int q = 0; q < 9; ++q) h2[q] = node2[((size_t)j2 * CH + c) * 9 + q];
            jnx = (p + 2 < end) ? jlist[p + 2] : 0;
        }

        // ---- compute with current edge ----
        float fc[NK];
#pragma unroll
        for (int k = 0; k < NK; ++k) {
            float s = 0.f;
#pragma unroll
            for (int b = 0; b < NB; ++b) s = fmaf(rbf[b], wreg[k * NB + b], s);
            fc[k] = s;
        }

        float u1 = ch1[0] * rh[0] + ch1[1] * rh[1] + ch1[2] * rh[2];
        float v2[3];
#pragma unroll
        for (int x = 0; x < 3; ++x)
            v2[x] = ch2[x * 3] * rh[0] + ch2[x * 3 + 1] * rh[1] + ch2[x * 3 + 2] * rh[2];
        float w2 = v2[0] * rh[0] + v2[1] * rh[1] + v2[2] * rh[2];

        a0 = fmaf(fc[0], ch0, a0);
        a0 = fmaf(fc[4], u1, a0);
        a0 = fmaf(fc[9], w2, a0);

        float c1 = fc[1] * ch0 + fc[6] * u1;
#pragma unroll
        for (int x = 0; x < 3; ++x)
            a1[x] += c1 * rh[x] + fc[3] * ch1[x] + fc[8] * v2[x];

#pragma unroll
        for (int x = 0; x < 3; ++x) {
            float cx = fc[2] * ch0 * rh[x] + fc[5] * ch1[x] + fc[10] * v2[x];
#pragma unroll
            for (int y = 0; y < 3; ++y)
                a2[x * 3 + y] += cx * rh[y] + fc[7] * ch2[x * 3 + y];
        }
    }

    // ---- stage scaled accumulators in LDS, [c][13] (stride 13: conflict-free) ----
    const float SC = 0.1f;  // 1/NORM_FACTOR
    abuf[c][0] = a0 * SC;
#pragma unroll
    for (int x = 0; x < 3; ++x) abuf[c][1 + x] = a1[x] * SC;
#pragma unroll
    for (int q = 0; q < 9; ++q) abuf[c][4 + q] = a2[q] * SC;

    __syncthreads();

    // ---- SI channel mixing (lane = output channel d) ----
    int d = c;
    float s0 = si_b0[d];
    float s1[3] = {0.f, 0.f, 0.f};
    float s2[9] = {0.f, 0.f, 0.f, 0.f, 0.f, 0.f, 0.f, 0.f, 0.f};

#pragma unroll 4
    for (int cc = 0; cc < CH; ++cc) {
        float w0 = si_w0[cc * CH + d];
        float w1 = si_w1[cc * CH + d];
        float w2m = si_w2[cc * CH + d];
        const float* a = abuf[cc];
        s0 = fmaf(a[0], w0, s0);
#pragma unroll
        for (int x = 0; x < 3; ++x) s1[x] = fmaf(a[1 + x], w1, s1[x]);
#pragma unroll
        for (int q = 0; q < 9; ++q) s2[q] = fmaf(a[4 + q], w2m, s2[q]);
    }

    float r0 = s0 / (1.0f + expf(-s0));

    float n1 = sqrtf(s1[0] * s1[0] + s1[1] * s1[1] + s1[2] * s1[2] + 1e-6f);
    float g1 = n1 * nl_w1[d] + nl_b1[d];
    float gate1 = g1 / (1.0f + expf(-g1));

    float n2sq = 1e-6f;
#pragma unroll
    for (int q = 0; q < 9; ++q) n2sq = fmaf(s2[q], s2[q], n2sq);
    float n2 = sqrtf(n2sq);
    float g2 = n2 * nl_w2[d] + nl_b2[d];
    float gate2 = g2 / (1.0f + expf(-g2));

    out0[(size_t)n * CH + d] = node0[(size_t)n * CH + d] + r0;
#pragma unroll
    for (int x = 0; x < 3; ++x)
        out1[((size_t)n * CH + d) * 3 + x] =
            node1[((size_t)n * CH + d) * 3 + x] + s1[x] * gate1;
#pragma unroll
    for (int q = 0; q < 9; ++q)
        out2[((size_t)n * CH + d) * 9 + q] =
            node2[((size_t)n * CH + d) * 9 + q] + s2[q] * gate2;
}

extern "C" void kernel_launch(void* const* d_in, const int* in_sizes, int n_in,
                              void* d_out, int out_size, void* d_ws, size_t ws_size,
                              hipStream_t stream) {
    const float* node0 = (const float*)d_in[0];
    const float* node1 = (const float*)d_in[1];
    const float* node2 = (const float*)d_in[2];
    const float* edge0 = (const float*)d_in[3];
    const float* rij   = (const float*)d_in[4];
    const int*   idx_i = (const int*)d_in[5];
    const int*   idx_j = (const int*)d_in[6];
    const float* rbf_w = (const float*)d_in[7];
    const float* si_w0 = (const float*)d_in[8];
    const float* si_b0 = (const float*)d_in[9];
    const float* si_w1 = (const float*)d_in[10];
    const float* si_w2 = (const float*)d_in[11];
    const float* nl_w1 = (const float*)d_in[12];
    const float* nl_b1 = (const float*)d_in[13];
    const float* nl_w2 = (const float*)d_in[14];
    const float* nl_b2 = (const float*)d_in[15];

    float* out = (float*)d_out;
    float* out0 = out;                                   // [A, C]
    float* out1 = out + (size_t)N_ATOMS * CH;            // [A, C, 3]
    float* out2 = out1 + (size_t)N_ATOMS * CH * 3;       // [A, C, 3, 3]
    float* oute = out2 + (size_t)N_ATOMS * CH * 9;       // [E, C]

    // workspace layout
    char* ws = (char*)d_ws;
    int* counts  = (int*)ws;                              ws += N_ATOMS * sizeof(int);
    int* cursor  = (int*)ws;                              ws += N_ATOMS * sizeof(int);
    int* offsets = (int*)ws;                              ws += (N_ATOMS + 1) * sizeof(int);
    ws = (char*)(((size_t)ws + 15) & ~(size_t)15);
    int* jlist   = (int*)ws;                              ws += N_EDGES * sizeof(int);
    ws = (char*)(((size_t)ws + 15) & ~(size_t)15);
    float4* ge4  = (float4*)ws;                           // 3 * N_EDGES float4

    hipMemsetAsync(counts, 0, N_ATOMS * sizeof(int), stream);

    hist_kernel<<<(N_EDGES + 255) / 256, 256, 0, stream>>>(idx_i, counts);

    scan_kernel<<<1, 1024, 0, stream>>>(counts, offsets, cursor);

    scatter_geom_kernel<<<(N_EDGES + 255) / 256, 256, 0, stream>>>(
        rij, idx_i, idx_j, cursor, jlist, ge4);

    atom_fused_kernel<<<N_ATOMS + COPY_BLOCKS, 64, 0, stream>>>(
        node0, node1, node2, jlist, offsets, ge4, rbf_w,
        si_w0, si_b0, si_w1, si_w2, nl_w1, nl_b1, nl_w2, nl_b2,
        out0, out1, out2,
        (const float4*)edge0, (float4*)oute);
}

// Round 8
// 244.123 us; speedup vs baseline: 1.2624x; 1.2624x over previous
//
#include <hip/hip_runtime.h>
#include <math.h>

#define N_ATOMS 20000
#define N_EDGES 200000
#define CH 64
#define NB 8
#define NK 11
#define ATOMS_PER_BLOCK 4
#define ATOM_BLOCKS (N_ATOMS / ATOMS_PER_BLOCK)   // 5000
#define COPY_F4 (N_EDGES * CH / 4)                // 3,200,000 float4
#define COPY_PER_BLOCK 1024                       // 256 threads x 4 float4
#define COPY_BLOCKS (COPY_F4 / COPY_PER_BLOCK)    // 3125

// ---------------------------------------------------------------
// Kernel 1: histogram of idx_i
__global__ __launch_bounds__(256) void hist_kernel(
    const int* __restrict__ idx_i, int* __restrict__ counts)
{
    int e = blockIdx.x * blockDim.x + threadIdx.x;
    if (e >= N_EDGES) return;
    atomicAdd(&counts[idx_i[e]], 1);
}

// ---------------------------------------------------------------
// Kernel 2: exclusive scan (single 1024-thread block)
__global__ __launch_bounds__(1024) void scan_kernel(
    const int* __restrict__ counts, int* __restrict__ offsets,
    int* __restrict__ cursor)
{
    __shared__ int part[1024];
    const int CHUNK = 20;  // 1024*20 = 20480 >= 20000
    int t = threadIdx.x;
    int beg = t * CHUNK;
    int s = 0;
    for (int k = 0; k < CHUNK; ++k) {
        int idx = beg + k;
        if (idx < N_ATOMS) s += counts[idx];
    }
    part[t] = s;
    __syncthreads();
    for (int off = 1; off < 1024; off <<= 1) {
        int v = (t >= off) ? part[t - off] : 0;
        __syncthreads();
        part[t] += v;
        __syncthreads();
    }
    int run = part[t] - s;
    for (int k = 0; k < CHUNK; ++k) {
        int idx = beg + k;
        if (idx < N_ATOMS) {
            offsets[idx] = run;
            cursor[idx] = run;
            run += counts[idx];
        }
    }
    if (t == 0) offsets[N_ATOMS] = N_EDGES;
}

// ---------------------------------------------------------------
// Kernel 3: scatter into CSR order, computing geometry on the fly
// ge4[p][0..2] = {rh, rbf0..7, pad}; jlist[p] = idx_j[e]
__global__ __launch_bounds__(256) void scatter_geom_kernel(
    const float* __restrict__ rij, const int* __restrict__ idx_i,
    const int* __restrict__ idx_j, int* __restrict__ cursor,
    int* __restrict__ jlist, float4* __restrict__ ge4)
{
    int e = blockIdx.x * blockDim.x + threadIdx.x;
    if (e >= N_EDGES) return;

    float rx = rij[e * 3 + 0];
    float ry = rij[e * 3 + 1];
    float rz = rij[e * 3 + 2];
    float d = sqrtf(rx * rx + ry * ry + rz * rz);
    float inv = 1.0f / (d + 1e-12f);

    float dc = fminf(d, 5.0f);
    float fcut = 0.5f * (cosf(3.14159265358979323846f * dc * 0.2f) + 1.0f);

    float rbf[NB];
#pragma unroll
    for (int b = 0; b < NB; ++b) {
        float mu = (5.0f / 7.0f) * (float)b;
        float t = d - mu;
        rbf[b] = expf(-2.0f * t * t) * fcut;
    }

    int p = atomicAdd(&cursor[idx_i[e]], 1);
    jlist[p] = idx_j[e];
    ge4[p * 3 + 0] = make_float4(rx * inv, ry * inv, rz * inv, rbf[0]);
    ge4[p * 3 + 1] = make_float4(rbf[1], rbf[2], rbf[3], rbf[4]);
    ge4[p * 3 + 2] = make_float4(rbf[5], rbf[6], rbf[7], 0.f);
}

// ---------------------------------------------------------------
// Kernel 4: fused gather + SI matmul + nonlinearity + residual.
// 256 threads = 4 INDEPENDENT waves, one atom each; rbf weights live
// in LDS (staged once per block). Blocks >= ATOM_BLOCKS copy edge0.
__global__ __launch_bounds__(256) void atom_fused_kernel(
    const float* __restrict__ node0, const float* __restrict__ node1,
    const float* __restrict__ node2,
    const int* __restrict__ jlist, const int* __restrict__ offsets,
    const float4* __restrict__ ge4, const float* __restrict__ rbf_w,
    const float* __restrict__ si_w0, const float* __restrict__ si_b0,
    const float* __restrict__ si_w1, const float* __restrict__ si_w2,
    const float* __restrict__ nl_w1, const float* __restrict__ nl_b1,
    const float* __restrict__ nl_w2, const float* __restrict__ nl_b2,
    float* __restrict__ out0, float* __restrict__ out1, float* __restrict__ out2,
    const float4* __restrict__ edge0_in, float4* __restrict__ edge0_out)
{
    int bid = blockIdx.x;

    if (bid >= ATOM_BLOCKS) {
        // edge0 passthrough: 1024 float4 per block (exact tiling)
        size_t base = (size_t)(bid - ATOM_BLOCKS) * COPY_PER_BLOCK;
#pragma unroll
        for (int k = 0; k < 4; ++k)
            edge0_out[base + k * 256 + threadIdx.x] =
                edge0_in[base + k * 256 + threadIdx.x];
        return;
    }

    __shared__ float wlds[NK * NB * CH];            // 11.25 KB: [k*NB+b][c]
    __shared__ float2 ab2[ATOMS_PER_BLOCK][CH][7];  // 14.0 KB: acc rows, pad 14

    // cooperative weight staging (11 dwords per thread), then one barrier;
    // after this the 4 waves are fully independent (no degree coupling).
    for (int t = threadIdx.x; t < NK * NB * CH; t += 256)
        wlds[t] = rbf_w[t];
    __syncthreads();

    int wv = threadIdx.x >> 6;
    int c = threadIdx.x & 63;
    int n = bid * ATOMS_PER_BLOCK + wv;   // N_ATOMS % 4 == 0

    float a0 = 0.f;
    float a1[3] = {0.f, 0.f, 0.f};
    float a2[9] = {0.f, 0.f, 0.f, 0.f, 0.f, 0.f, 0.f, 0.f, 0.f};

    int beg = offsets[n];
    int end = offsets[n + 1];

    // software pipeline: geom + h for edge p, j for edge p+1
    float4 g0, g1v, g2v;
    float h0 = 0.f, h1[3] = {0.f, 0.f, 0.f};
    float h2[9] = {0.f, 0.f, 0.f, 0.f, 0.f, 0.f, 0.f, 0.f, 0.f};
    int jnx = 0;

    if (beg < end) {
        int j = jlist[beg];
        g0 = ge4[beg * 3 + 0];
        g1v = ge4[beg * 3 + 1];
        g2v = ge4[beg * 3 + 2];
        h0 = node0[(size_t)j * CH + c];
#pragma unroll
        for (int x = 0; x < 3; ++x) h1[x] = node1[((size_t)j * CH + c) * 3 + x];
#pragma unroll
        for (int q = 0; q < 9; ++q) h2[q] = node2[((size_t)j * CH + c) * 9 + q];
        jnx = (beg + 1 < end) ? jlist[beg + 1] : 0;
    }

    for (int p = beg; p < end; ++p) {
        float rh[3] = {g0.x, g0.y, g0.z};
        float rbf[NB] = {g0.w, g1v.x, g1v.y, g1v.z, g1v.w, g2v.x, g2v.y, g2v.z};
        float ch0 = h0;
        float ch1[3] = {h1[0], h1[1], h1[2]};
        float ch2[9];
#pragma unroll
        for (int q = 0; q < 9; ++q) ch2[q] = h2[q];

        if (p + 1 < end) {
            int j2 = jnx;
            g0 = ge4[(p + 1) * 3 + 0];
            g1v = ge4[(p + 1) * 3 + 1];
            g2v = ge4[(p + 1) * 3 + 2];
            h0 = node0[(size_t)j2 * CH + c];
#pragma unroll
            for (int x = 0; x < 3; ++x) h1[x] = node1[((size_t)j2 * CH + c) * 3 + x];
#pragma unroll
            for (int q = 0; q < 9; ++q) h2[q] = node2[((size_t)j2 * CH + c) * 9 + q];
            jnx = (p + 2 < end) ? jlist[p + 2] : 0;
        }

        // ---- fc from LDS weights: 88 ds_read_b32, lane-stride-1 (no
        // conflicts). The opaque lane index stops LICM from hoisting the
        // loads back into registers (the R3-R7 spill/remat trap). ----
        int cop = c;
        asm volatile("" : "+v"(cop));
        const float* wl = &wlds[cop];

        float fc[NK];
#pragma unroll
        for (int k = 0; k < NK; ++k) {
            float s = 0.f;
#pragma unroll
            for (int b = 0; b < NB; ++b)
                s = fmaf(rbf[b], wl[(k * NB + b) * CH], s);
            fc[k] = s;
        }

        float u1 = ch1[0] * rh[0] + ch1[1] * rh[1] + ch1[2] * rh[2];
        float v2[3];
#pragma unroll
        for (int x = 0; x < 3; ++x)
            v2[x] = ch2[x * 3] * rh[0] + ch2[x * 3 + 1] * rh[1] + ch2[x * 3 + 2] * rh[2];
        float w2 = v2[0] * rh[0] + v2[1] * rh[1] + v2[2] * rh[2];

        a0 = fmaf(fc[0], ch0, a0);
        a0 = fmaf(fc[4], u1, a0);
        a0 = fmaf(fc[9], w2, a0);

        float c1 = fc[1] * ch0 + fc[6] * u1;
#pragma unroll
        for (int x = 0; x < 3; ++x)
            a1[x] += c1 * rh[x] + fc[3] * ch1[x] + fc[8] * v2[x];

#pragma unroll
        for (int x = 0; x < 3; ++x) {
            float cx = fc[2] * ch0 * rh[x] + fc[5] * ch1[x] + fc[10] * v2[x];
#pragma unroll
            for (int y = 0; y < 3; ++y)
                a2[x * 3 + y] += cx * rh[y] + fc[7] * ch2[x * 3 + y];
        }
    }

    // ---- stage scaled accumulators: row of 14 floats (7 float2), 8B-aligned ----
    const float SC = 0.1f;  // 1/NORM_FACTOR
    ab2[wv][c][0] = make_float2(a0 * SC, a1[0] * SC);
    ab2[wv][c][1] = make_float2(a1[1] * SC, a1[2] * SC);
    ab2[wv][c][2] = make_float2(a2[0] * SC, a2[1] * SC);
    ab2[wv][c][3] = make_float2(a2[2] * SC, a2[3] * SC);
    ab2[wv][c][4] = make_float2(a2[4] * SC, a2[5] * SC);
    ab2[wv][c][5] = make_float2(a2[6] * SC, a2[7] * SC);
    ab2[wv][c][6] = make_float2(a2[8] * SC, 0.f);

    // in-wave cross-lane LDS handoff: DS ops from one wave complete in
    // order; wave_barrier pins compile-time ordering. No __syncthreads
    // (waves own disjoint ab2 slices; avoids degree-imbalance coupling).
    __builtin_amdgcn_wave_barrier();

    // ---- SI channel mixing (lane = output channel c of atom n) ----
    float s0 = si_b0[c];
    float s1[3] = {0.f, 0.f, 0.f};
    float s2[9] = {0.f, 0.f, 0.f, 0.f, 0.f, 0.f, 0.f, 0.f, 0.f};

    for (int cc = 0; cc < CH; ++cc) {
        float2 q0 = ab2[wv][cc][0];
        float2 q1 = ab2[wv][cc][1];
        float2 q2 = ab2[wv][cc][2];
        float2 q3 = ab2[wv][cc][3];
        float2 q4 = ab2[wv][cc][4];
        float2 q5 = ab2[wv][cc][5];
        float2 q6 = ab2[wv][cc][6];
        float w0 = si_w0[cc * CH + c];
        float w1 = si_w1[cc * CH + c];
        float w2m = si_w2[cc * CH + c];
        s0 = fmaf(q0.x, w0, s0);
        s1[0] = fmaf(q0.y, w1, s1[0]);
        s1[1] = fmaf(q1.x, w1, s1[1]);
        s1[2] = fmaf(q1.y, w1, s1[2]);
        s2[0] = fmaf(q2.x, w2m, s2[0]);
        s2[1] = fmaf(q2.y, w2m, s2[1]);
        s2[2] = fmaf(q3.x, w2m, s2[2]);
        s2[3] = fmaf(q3.y, w2m, s2[3]);
        s2[4] = fmaf(q4.x, w2m, s2[4]);
        s2[5] = fmaf(q4.y, w2m, s2[5]);
        s2[6] = fmaf(q5.x, w2m, s2[6]);
        s2[7] = fmaf(q5.y, w2m, s2[7]);
        s2[8] = fmaf(q6.x, w2m, s2[8]);
    }

    float r0 = s0 / (1.0f + expf(-s0));

    float n1 = sqrtf(s1[0] * s1[0] + s1[1] * s1[1] + s1[2] * s1[2] + 1e-6f);
    float g1 = n1 * nl_w1[c] + nl_b1[c];
    float gate1 = g1 / (1.0f + expf(-g1));

    float n2sq = 1e-6f;
#pragma unroll
    for (int q = 0; q < 9; ++q) n2sq = fmaf(s2[q], s2[q], n2sq);
    float n2 = sqrtf(n2sq);
    float g2 = n2 * nl_w2[c] + nl_b2[c];
    float gate2 = g2 / (1.0f + expf(-g2));

    out0[(size_t)n * CH + c] = node0[(size_t)n * CH + c] + r0;
#pragma unroll
    for (int x = 0; x < 3; ++x)
        out1[((size_t)n * CH + c) * 3 + x] =
            node1[((size_t)n * CH + c) * 3 + x] + s1[x] * gate1;
#pragma unroll
    for (int q = 0; q < 9; ++q)
        out2[((size_t)n * CH + c) * 9 + q] =
            node2[((size_t)n * CH + c) * 9 + q] + s2[q] * gate2;
}

extern "C" void kernel_launch(void* const* d_in, const int* in_sizes, int n_in,
                              void* d_out, int out_size, void* d_ws, size_t ws_size,
                              hipStream_t stream) {
    const float* node0 = (const float*)d_in[0];
    const float* node1 = (const float*)d_in[1];
    const float* node2 = (const float*)d_in[2];
    const float* edge0 = (const float*)d_in[3];
    const float* rij   = (const float*)d_in[4];
    const int*   idx_i = (const int*)d_in[5];
    const int*   idx_j = (const int*)d_in[6];
    const float* rbf_w = (const float*)d_in[7];
    const float* si_w0 = (const float*)d_in[8];
    const float* si_b0 = (const float*)d_in[9];
    const float* si_w1 = (const float*)d_in[10];
    const float* si_w2 = (const float*)d_in[11];
    const float* nl_w1 = (const float*)d_in[12];
    const float* nl_b1 = (const float*)d_in[13];
    const float* nl_w2 = (const float*)d_in[14];
    const float* nl_b2 = (const float*)d_in[15];

    float* out = (float*)d_out;
    float* out0 = out;                                   // [A, C]
    float* out1 = out + (size_t)N_ATOMS * CH;            // [A, C, 3]
    float* out2 = out1 + (size_t)N_ATOMS * CH * 3;       // [A, C, 3, 3]
    float* oute = out2 + (size_t)N_ATOMS * CH * 9;       // [E, C]

    // workspace layout
    char* ws = (char*)d_ws;
    int* counts  = (int*)ws;                              ws += N_ATOMS * sizeof(int);
    int* cursor  = (int*)ws;                              ws += N_ATOMS * sizeof(int);
    int* offsets = (int*)ws;                              ws += (N_ATOMS + 1) * sizeof(int);
    ws = (char*)(((size_t)ws + 15) & ~(size_t)15);
    int* jlist   = (int*)ws;                              ws += N_EDGES * sizeof(int);
    ws = (char*)(((size_t)ws + 15) & ~(size_t)15);
    float4* ge4  = (float4*)ws;                           // 3 * N_EDGES float4

    hipMemsetAsync(counts, 0, N_ATOMS * sizeof(int), stream);

    hist_kernel<<<(N_EDGES + 255) / 256, 256, 0, stream>>>(idx_i, counts);

    scan_kernel<<<1, 1024, 0, stream>>>(counts, offsets, cursor);

    scatter_geom_kernel<<<(N_EDGES + 255) / 256, 256, 0, stream>>>(
        rij, idx_i, idx_j, cursor, jlist, ge4);

    atom_fused_kernel<<<ATOM_BLOCKS + COPY_BLOCKS, 256, 0, stream>>>(
        node0, node1, node2, jlist, offsets, ge4, rbf_w,
        si_w0, si_b0, si_w1, si_w2, nl_w1, nl_b1, nl_w2, nl_b2,
        out0, out1, out2,
        (const float4*)edge0, (float4*)oute);
}

// Round 10
// 212.433 us; speedup vs baseline: 1.4507x; 1.1492x over previous
//
#include <hip/hip_runtime.h>
#include <math.h>

#define N_ATOMS 20000
#define N_EDGES 200000
#define CH 64
#define NB 8
#define NK 11
#define ATOMS_PER_BLOCK 4
#define ATOM_BLOCKS (N_ATOMS / ATOMS_PER_BLOCK)   // 5000
#define COPY_F4 (N_EDGES * CH / 4)                // 3,200,000 float4
#define COPY_PER_BLOCK 1024                       // 256 threads x 4 float4
#define COPY_BLOCKS (COPY_F4 / COPY_PER_BLOCK)    // 3125

#define WSTRIDE 44   // dwords per lane of packed f16 weights (88 halves)

typedef _Float16 h2 __attribute__((ext_vector_type(2)));   // fdot2 operand type
typedef __fp16  p2 __attribute__((ext_vector_type(2)));    // cvt_pkrtz result type

union F2H { float f; h2 h; p2 p; unsigned int u; };

static __device__ __forceinline__ h2 pack_f16(float a, float b) {
    F2H u;
    u.p = __builtin_amdgcn_cvt_pkrtz(a, b);
    return u.h;
}

// ---------------------------------------------------------------
// Kernel 1: histogram of idx_i
__global__ __launch_bounds__(256) void hist_kernel(
    const int* __restrict__ idx_i, int* __restrict__ counts)
{
    int e = blockIdx.x * blockDim.x + threadIdx.x;
    if (e >= N_EDGES) return;
    atomicAdd(&counts[idx_i[e]], 1);
}

// ---------------------------------------------------------------
// Kernel 2: exclusive scan (single 1024-thread block)
__global__ __launch_bounds__(1024) void scan_kernel(
    const int* __restrict__ counts, int* __restrict__ offsets,
    int* __restrict__ cursor)
{
    __shared__ int part[1024];
    const int CHUNK = 20;  // 1024*20 = 20480 >= 20000
    int t = threadIdx.x;
    int beg = t * CHUNK;
    int s = 0;
    for (int k = 0; k < CHUNK; ++k) {
        int idx = beg + k;
        if (idx < N_ATOMS) s += counts[idx];
    }
    part[t] = s;
    __syncthreads();
    for (int off = 1; off < 1024; off <<= 1) {
        int v = (t >= off) ? part[t - off] : 0;
        __syncthreads();
        part[t] += v;
        __syncthreads();
    }
    int run = part[t] - s;
    for (int k = 0; k < CHUNK; ++k) {
        int idx = beg + k;
        if (idx < N_ATOMS) {
            offsets[idx] = run;
            cursor[idx] = run;
            run += counts[idx];
        }
    }
    if (t == 0) offsets[N_ATOMS] = N_EDGES;
}

// ---------------------------------------------------------------
// Kernel 3: scatter into CSR order, computing geometry on the fly
// ge4[p][0..2] = {rh, rbf0..7, pad}; jlist[p] = idx_j[e]
__global__ __launch_bounds__(256) void scatter_geom_kernel(
    const float* __restrict__ rij, const int* __restrict__ idx_i,
    const int* __restrict__ idx_j, int* __restrict__ cursor,
    int* __restrict__ jlist, float4* __restrict__ ge4)
{
    int e = blockIdx.x * blockDim.x + threadIdx.x;
    if (e >= N_EDGES) return;

    float rx = rij[e * 3 + 0];
    float ry = rij[e * 3 + 1];
    float rz = rij[e * 3 + 2];
    float d = sqrtf(rx * rx + ry * ry + rz * rz);
    float inv = 1.0f / (d + 1e-12f);

    float dc = fminf(d, 5.0f);
    float fcut = 0.5f * (cosf(3.14159265358979323846f * dc * 0.2f) + 1.0f);

    float rbf[NB];
#pragma unroll
    for (int b = 0; b < NB; ++b) {
        float mu = (5.0f / 7.0f) * (float)b;
        float t = d - mu;
        rbf[b] = expf(-2.0f * t * t) * fcut;
    }

    int p = atomicAdd(&cursor[idx_i[e]], 1);
    jlist[p] = idx_j[e];
    ge4[p * 3 + 0] = make_float4(rx * inv, ry * inv, rz * inv, rbf[0]);
    ge4[p * 3 + 1] = make_float4(rbf[1], rbf[2], rbf[3], rbf[4]);
    ge4[p * 3 + 2] = make_float4(rbf[5], rbf[6], rbf[7], 0.f);
}

// ---------------------------------------------------------------
// Kernel 4: fused gather + SI matmul + nonlinearity + residual.
// 256 threads = 4 independent waves, one atom each. rbf weights are
// f16-packed in LDS, per-lane-contiguous: lane c reads its 88 halves
// as 11 x ds_read_b128 per edge (layout [c][WSTRIDE dwords], stride
// 44 % 32 = 12 -> wave's 256 dwords spread evenly over 32 banks).
// fc via v_dot2_f32_f16. Blocks >= ATOM_BLOCKS copy edge0.
__global__ __launch_bounds__(256) void atom_fused_kernel(
    const float* __restrict__ node0, const float* __restrict__ node1,
    const float* __restrict__ node2,
    const int* __restrict__ jlist, const int* __restrict__ offsets,
    const float4* __restrict__ ge4, const float* __restrict__ rbf_w,
    const float* __restrict__ si_w0, const float* __restrict__ si_b0,
    const float* __restrict__ si_w1, const float* __restrict__ si_w2,
    const float* __restrict__ nl_w1, const float* __restrict__ nl_b1,
    const float* __restrict__ nl_w2, const float* __restrict__ nl_b2,
    float* __restrict__ out0, float* __restrict__ out1, float* __restrict__ out2,
    const float4* __restrict__ edge0_in, float4* __restrict__ edge0_out)
{
    int bid = blockIdx.x;

    if (bid >= ATOM_BLOCKS) {
        size_t base = (size_t)(bid - ATOM_BLOCKS) * COPY_PER_BLOCK;
#pragma unroll
        for (int k = 0; k < 4; ++k)
            edge0_out[base + k * 256 + threadIdx.x] =
                edge0_in[base + k * 256 + threadIdx.x];
        return;
    }

    __shared__ __align__(16) float wlds[CH * WSTRIDE]; // 11.0 KB packed f16 weights
    __shared__ float2 ab2[ATOMS_PER_BLOCK][CH][7];     // 14.0 KB acc handoff

    int wv = threadIdx.x >> 6;
    int c = threadIdx.x & 63;

    // ---- stage weights: dword kd of lane c holds halves (k, 2j),(k, 2j+1)
    // with k = kd>>2, j = kd&3, value rbf_w[(k*8+b)*CH + c] cvt to f16 ----
    {
        for (int kd = wv; kd < WSTRIDE; kd += 4) {
            int k = kd >> 2, j = kd & 3;
            float w0 = rbf_w[(k * NB + 2 * j) * CH + c];
            float w1 = rbf_w[(k * NB + 2 * j + 1) * CH + c];
            F2H u;
            u.p = __builtin_amdgcn_cvt_pkrtz(w0, w1);
            wlds[c * WSTRIDE + kd] = u.f;
        }
    }
    __syncthreads();

    int n = bid * ATOMS_PER_BLOCK + wv;   // N_ATOMS % 4 == 0

    float a0 = 0.f;
    float a1[3] = {0.f, 0.f, 0.f};
    float a2[9] = {0.f, 0.f, 0.f, 0.f, 0.f, 0.f, 0.f, 0.f, 0.f};

    int beg = offsets[n];
    int end = offsets[n + 1];

    // software pipeline: geom + h for edge p, j for edge p+1
    float4 g0, g1v, g2v;
    float h0 = 0.f, h1[3] = {0.f, 0.f, 0.f};
    float h2v[9] = {0.f, 0.f, 0.f, 0.f, 0.f, 0.f, 0.f, 0.f, 0.f};
    int jnx = 0;

    if (beg < end) {
        int j = jlist[beg];
        g0 = ge4[beg * 3 + 0];
        g1v = ge4[beg * 3 + 1];
        g2v = ge4[beg * 3 + 2];
        h0 = node0[(size_t)j * CH + c];
#pragma unroll
        for (int x = 0; x < 3; ++x) h1[x] = node1[((size_t)j * CH + c) * 3 + x];
#pragma unroll
        for (int q = 0; q < 9; ++q) h2v[q] = node2[((size_t)j * CH + c) * 9 + q];
        jnx = (beg + 1 < end) ? jlist[beg + 1] : 0;
    }

    for (int p = beg; p < end; ++p) {
        float rh[3] = {g0.x, g0.y, g0.z};
        float rbf[NB] = {g0.w, g1v.x, g1v.y, g1v.z, g1v.w, g2v.x, g2v.y, g2v.z};
        float ch0 = h0;
        float ch1[3] = {h1[0], h1[1], h1[2]};
        float ch2[9];
#pragma unroll
        for (int q = 0; q < 9; ++q) ch2[q] = h2v[q];

        if (p + 1 < end) {
            int j2 = jnx;
            g0 = ge4[(p + 1) * 3 + 0];
            g1v = ge4[(p + 1) * 3 + 1];
            g2v = ge4[(p + 1) * 3 + 2];
            h0 = node0[(size_t)j2 * CH + c];
#pragma unroll
            for (int x = 0; x < 3; ++x) h1[x] = node1[((size_t)j2 * CH + c) * 3 + x];
#pragma unroll
            for (int q = 0; q < 9; ++q) h2v[q] = node2[((size_t)j2 * CH + c) * 9 + q];
            jnx = (p + 2 < end) ? jlist[p + 2] : 0;
        }

        // ---- rbf to f16 pairs (lane-uniform values) ----
        h2 rb[4];
        rb[0] = pack_f16(rbf[0], rbf[1]);
        rb[1] = pack_f16(rbf[2], rbf[3]);
        rb[2] = pack_f16(rbf[4], rbf[5]);
        rb[3] = pack_f16(rbf[6], rbf[7]);

        // ---- fc from LDS: 11 x ds_read_b128, 4 x fdot2 each. The opaque
        // lane index keeps LICM from hoisting the reads (R3-R7 trap). ----
        int cop = c;
        asm volatile("" : "+v"(cop));
        const float4* wp4 = reinterpret_cast<const float4*>(&wlds[cop * WSTRIDE]);

        float fc[NK];
#pragma unroll
        for (int k = 0; k < NK; ++k) {
            float4 w = wp4[k];
            F2H u0, u1_, u2, u3;
            u0.f = w.x; u1_.f = w.y; u2.f = w.z; u3.f = w.w;
            float s = __builtin_amdgcn_fdot2(rb[0], u0.h, 0.f, false);
            s = __builtin_amdgcn_fdot2(rb[1], u1_.h, s, false);
            s = __builtin_amdgcn_fdot2(rb[2], u2.h, s, false);
            fc[k] = __builtin_amdgcn_fdot2(rb[3], u3.h, s, false);
        }

        float u1 = ch1[0] * rh[0] + ch1[1] * rh[1] + ch1[2] * rh[2];
        float v2[3];
#pragma unroll
        for (int x = 0; x < 3; ++x)
            v2[x] = ch2[x * 3] * rh[0] + ch2[x * 3 + 1] * rh[1] + ch2[x * 3 + 2] * rh[2];
        float w2 = v2[0] * rh[0] + v2[1] * rh[1] + v2[2] * rh[2];

        a0 = fmaf(fc[0], ch0, a0);
        a0 = fmaf(fc[4], u1, a0);
        a0 = fmaf(fc[9], w2, a0);

        float c1 = fc[1] * ch0 + fc[6] * u1;
#pragma unroll
        for (int x = 0; x < 3; ++x)
            a1[x] += c1 * rh[x] + fc[3] * ch1[x] + fc[8] * v2[x];

#pragma unroll
        for (int x = 0; x < 3; ++x) {
            float cx = fc[2] * ch0 * rh[x] + fc[5] * ch1[x] + fc[10] * v2[x];
#pragma unroll
            for (int y = 0; y < 3; ++y)
                a2[x * 3 + y] += cx * rh[y] + fc[7] * ch2[x * 3 + y];
        }
    }

    // ---- stage scaled accumulators: 7 float2 per channel ----
    const float SC = 0.1f;  // 1/NORM_FACTOR
    ab2[wv][c][0] = make_float2(a0 * SC, a1[0] * SC);
    ab2[wv][c][1] = make_float2(a1[1] * SC, a1[2] * SC);
    ab2[wv][c][2] = make_float2(a2[0] * SC, a2[1] * SC);
    ab2[wv][c][3] = make_float2(a2[2] * SC, a2[3] * SC);
    ab2[wv][c][4] = make_float2(a2[4] * SC, a2[5] * SC);
    ab2[wv][c][5] = make_float2(a2[6] * SC, a2[7] * SC);
    ab2[wv][c][6] = make_float2(a2[8] * SC, 0.f);

    // in-wave cross-lane handoff (waves own disjoint ab2 slices)
    __builtin_amdgcn_wave_barrier();

    // ---- SI channel mixing (lane = output channel c of atom n) ----
    float s0 = si_b0[c];
    float s1[3] = {0.f, 0.f, 0.f};
    float s2[9] = {0.f, 0.f, 0.f, 0.f, 0.f, 0.f, 0.f, 0.f, 0.f};

    for (int cc = 0; cc < CH; ++cc) {
        float2 q0 = ab2[wv][cc][0];
        float2 q1 = ab2[wv][cc][1];
        float2 q2 = ab2[wv][cc][2];
        float2 q3 = ab2[wv][cc][3];
        float2 q4 = ab2[wv][cc][4];
        float2 q5 = ab2[wv][cc][5];
        float2 q6 = ab2[wv][cc][6];
        float w0 = si_w0[cc * CH + c];
        float w1 = si_w1[cc * CH + c];
        float w2m = si_w2[cc * CH + c];
        s0 = fmaf(q0.x, w0, s0);
        s1[0] = fmaf(q0.y, w1, s1[0]);
        s1[1] = fmaf(q1.x, w1, s1[1]);
        s1[2] = fmaf(q1.y, w1, s1[2]);
        s2[0] = fmaf(q2.x, w2m, s2[0]);
        s2[1] = fmaf(q2.y, w2m, s2[1]);
        s2[2] = fmaf(q3.x, w2m, s2[2]);
        s2[3] = fmaf(q3.y, w2m, s2[3]);
        s2[4] = fmaf(q4.x, w2m, s2[4]);
        s2[5] = fmaf(q4.y, w2m, s2[5]);
        s2[6] = fmaf(q5.x, w2m, s2[6]);
        s2[7] = fmaf(q5.y, w2m, s2[7]);
        s2[8] = fmaf(q6.x, w2m, s2[8]);
    }

    float r0 = s0 / (1.0f + expf(-s0));

    float n1 = sqrtf(s1[0] * s1[0] + s1[1] * s1[1] + s1[2] * s1[2] + 1e-6f);
    float g1 = n1 * nl_w1[c] + nl_b1[c];
    float gate1 = g1 / (1.0f + expf(-g1));

    float n2sq = 1e-6f;
#pragma unroll
    for (int q = 0; q < 9; ++q) n2sq = fmaf(s2[q], s2[q], n2sq);
    float n2 = sqrtf(n2sq);
    float g2 = n2 * nl_w2[c] + nl_b2[c];
    float gate2 = g2 / (1.0f + expf(-g2));

    out0[(size_t)n * CH + c] = node0[(size_t)n * CH + c] + r0;
#pragma unroll
    for (int x = 0; x < 3; ++x)
        out1[((size_t)n * CH + c) * 3 + x] =
            node1[((size_t)n * CH + c) * 3 + x] + s1[x] * gate1;
#pragma unroll
    for (int q = 0; q < 9; ++q)
        out2[((size_t)n * CH + c) * 9 + q] =
            node2[((size_t)n * CH + c) * 9 + q] + s2[q] * gate2;
}

extern "C" void kernel_launch(void* const* d_in, const int* in_sizes, int n_in,
                              void* d_out, int out_size, void* d_ws, size_t ws_size,
                              hipStream_t stream) {
    const float* node0 = (const float*)d_in[0];
    const float* node1 = (const float*)d_in[1];
    const float* node2 = (const float*)d_in[2];
    const float* edge0 = (const float*)d_in[3];
    const float* rij   = (const float*)d_in[4];
    const int*   idx_i = (const int*)d_in[5];
    const int*   idx_j = (const int*)d_in[6];
    const float* rbf_w = (const float*)d_in[7];
    const float* si_w0 = (const float*)d_in[8];
    const float* si_b0 = (const float*)d_in[9];
    const float* si_w1 = (const float*)d_in[10];
    const float* si_w2 = (const float*)d_in[11];
    const float* nl_w1 = (const float*)d_in[12];
    const float* nl_b1 = (const float*)d_in[13];
    const float* nl_w2 = (const float*)d_in[14];
    const float* nl_b2 = (const float*)d_in[15];

    float* out = (float*)d_out;
    float* out0 = out;                                   // [A, C]
    float* out1 = out + (size_t)N_ATOMS * CH;            // [A, C, 3]
    float* out2 = out1 + (size_t)N_ATOMS * CH * 3;       // [A, C, 3, 3]
    float* oute = out2 + (size_t)N_ATOMS * CH * 9;       // [E, C]

    // workspace layout
    char* ws = (char*)d_ws;
    int* counts  = (int*)ws;                              ws += N_ATOMS * sizeof(int);
    int* cursor  = (int*)ws;                              ws += N_ATOMS * sizeof(int);
    int* offsets = (int*)ws;                              ws += (N_ATOMS + 1) * sizeof(int);
    ws = (char*)(((size_t)ws + 15) & ~(size_t)15);
    int* jlist   = (int*)ws;                              ws += N_EDGES * sizeof(int);
    ws = (char*)(((size_t)ws + 15) & ~(size_t)15);
    float4* ge4  = (float4*)ws;                           // 3 * N_EDGES float4

    hipMemsetAsync(counts, 0, N_ATOMS * sizeof(int), stream);

    hist_kernel<<<(N_EDGES + 255) / 256, 256, 0, stream>>>(idx_i, counts);

    scan_kernel<<<1, 1024, 0, stream>>>(counts, offsets, cursor);

    scatter_geom_kernel<<<(N_EDGES + 255) / 256, 256, 0, stream>>>(
        rij, idx_i, idx_j, cursor, jlist, ge4);

    atom_fused_kernel<<<ATOM_BLOCKS + COPY_BLOCKS, 256, 0, stream>>>(
        node0, node1, node2, jlist, offsets, ge4, rbf_w,
        si_w0, si_b0, si_w1, si_w2, nl_w1, nl_b1, nl_w2, nl_b2,
        out0, out1, out2,
        (const float4*)edge0, (float4*)oute);
}